// Round 3
// baseline (221.078 us; speedup 1.0000x reference)
//
#include <hip/hip_runtime.h>

// Transposed flash attention, f16 MFMA (16x16x32), no-max softmax, split-K=2.
// R13: BARRIER-FREE. R11 (split-4) and R12 (smaller slab, +40% occupancy)
// both left time flat at ~85us -> occupancy was never the limit. Pipe math:
// MFMA needs ~79k cyc/SIMD, VALU ~81k, measured 204k -> 2.5x serialization
// from the lockstep structure (4 waves ganged at 2 barriers/2-tiles, serial
// ds_read->QK->exp->PV chain per interval). Fix: K/V images are ALREADY in
// exact per-lane fragment layout in global memory -- read kf/vf straight
// from L2 with global_load_dwordx4 (constant per-lane offsets, base advances
// 8KB/tile). Removes ALL barriers, ds_reads, staging, LDS (->0). Waves fully
// independent; 2/SIMD cover each other's L2 latency (~1240 cyc MFMA/tile).
// XCD decode clusters blocks by batch: XCD x holds b in {x, x+8} -> 2MB
// image working set per 4MB L2. Image swizzle dropped (was only for LDS
// banks; linear layout = coalesced 64B row segments). s=4 geometry (BQ=256,
// grid 512) keeps K/V L2 volume at 1GB (~29us aggregate, 50% headroom; s=2
// would double it onto the L2 roof). T5 setprio around MFMA clusters (m191:
// +4-7% on independent-wave attn). Numerics bit-identical to R10.
// launch_bounds(256,2): ~190 live regs vs 256 cap, no spill risk (R9!).
// Failure reads: FETCH_SIZE >> 150MB -> XCD clustering failed, L2 thrash;
// flat time+util -> loads not hoisted, add explicit t+1 register prefetch.

#define NBATCH 16
#define SEQ    4096
#define DIM    64
#define BQ     256
#define BK     64
#define NKT    (SEQ / BK)      // 64
#define KHALF  (NKT / 2)       // 32 tiles per key-half
#define OELEMS (NBATCH * SEQ * DIM)   // 4194304
#define NROWS  (NBATCH * SEQ)         // 65536
#define NTILES (NBATCH * NKT)         // 1024
#define TILEH  4096                   // halfs per 64x64 tile image (8 KB)

#define QSCALE 0.180336879f   // 0.125 * log2(e)

typedef _Float16 half2_t __attribute__((ext_vector_type(2)));
typedef _Float16 half4_t __attribute__((ext_vector_type(4)));
typedef _Float16 half8_t __attribute__((ext_vector_type(8)));
typedef float    floatx4 __attribute__((ext_vector_type(4)));

__device__ inline float fast_exp2(float x) {
#if __has_builtin(__builtin_amdgcn_exp2f)
  return __builtin_amdgcn_exp2f(x);
#else
  return exp2f(x);
#endif
}
__device__ inline float fast_rcp(float x) {
#if __has_builtin(__builtin_amdgcn_rcpf)
  return __builtin_amdgcn_rcpf(x);
#else
  return 1.0f / x;
#endif
}

// R13: identity layout (swizzle was only needed for LDS bank conflicts;
// global loads want linear rows for coalescing). Writer+reader both changed
// -> logical tile content identical, numerics bit-identical.
__device__ inline int swz(int row, int col) { return row * 64 + col; }

// ---------------- prepack: K,V f32 -> per-tile f16 images ----------------
// One block per (b, kt) tile. K: [key][dim]; V: [dim][slot] (slot-permuted
// PV fragment layout). Staged through LDS for coalesced global dump.
__global__ __launch_bounds__(256, 2)
void prepack_kv(const float* __restrict__ Kg, const float* __restrict__ Vg,
                _Float16* __restrict__ Kh, _Float16* __restrict__ Vh)
{
  __shared__ __align__(16) _Float16 sKi[TILEH];
  __shared__ __align__(16) _Float16 sVi[TILEH];
  const int tid = threadIdx.x;
  const int t16 = tid & 15;
  const int kg  = tid >> 4;
  const int bt  = blockIdx.x;                 // b*64 + kt
  const float* Kt_ = Kg + (size_t)bt * BK * DIM;
  const float* Vt_ = Vg + (size_t)bt * BK * DIM;

  floatx4 kbuf[4], vbuf[4];
  #pragma unroll
  for (int i = 0; i < 4; ++i) {
    const int key = kg + 16 * i;
    kbuf[i] = *(const floatx4*)(Kt_ + key * DIM + t16 * 4);
    vbuf[i] = *(const floatx4*)(Vt_ + key * DIM + t16 * 4);
  }
  #pragma unroll
  for (int i = 0; i < 4; ++i) {               // K: [key][dim]
    const int key = kg + 16 * i;
    half4_t h;
    #pragma unroll
    for (int j = 0; j < 4; ++j) h[j] = (_Float16)kbuf[i][j];
    *(half4_t*)&sKi[swz(key, t16 * 4)] = h;
  }
  {                                           // V: [dim][slot]
    const int vbase = (kg >> 2) * 8 + (kg & 3) * 2;
    #pragma unroll
    for (int e = 0; e < 4; ++e) {
      const int dim = t16 * 4 + e;
      half2_t h0; h0[0] = (_Float16)vbuf[0][e]; h0[1] = (_Float16)vbuf[1][e];
      half2_t h1; h1[0] = (_Float16)vbuf[2][e]; h1[1] = (_Float16)vbuf[3][e];
      *(half2_t*)&sVi[swz(dim, vbase)]      = h0;
      *(half2_t*)&sVi[swz(dim, vbase + 32)] = h1;
    }
  }
  __syncthreads();
  half8_t* Ko = (half8_t*)(Kh + (size_t)bt * TILEH);
  half8_t* Vo = (half8_t*)(Vh + (size_t)bt * TILEH);
  const half8_t* Ks = (const half8_t*)sKi;
  const half8_t* Vs = (const half8_t*)sVi;
  Ko[tid] = Ks[tid]; Ko[tid + 256] = Ks[tid + 256];
  Vo[tid] = Vs[tid]; Vo[tid + 256] = Vs[tid + 256];
}

// ---------------- main kernel: barrier-free, LDS-free ----------------
// 4 independent waves/block, each owns 64 q-rows (4 slabs of 16), streams
// K/V fragments straight from L2-resident prepacked images.
__global__ __launch_bounds__(256, 2)
void attn_f16_flash(const float* __restrict__ Qg, const _Float16* __restrict__ Kh,
                    const _Float16* __restrict__ Vh, float* __restrict__ O0g,
                    float* __restrict__ O1g, float* __restrict__ lsg)
{
  const int tid  = threadIdx.x;
  const int wave = tid >> 6;
  const int lane = tid & 63;
  const int l16  = lane & 15;
  const int quad = lane >> 4;

  // XCD-clustered decode (bijective over 512 blocks): XCD x = bid&7 gets
  // batches {x, x+8} only -> 2MB K/V image working set per 4MB XCD L2.
  const int bid  = blockIdx.x;
  const int x    = bid & 7;
  const int r    = bid >> 3;                // 0..63
  const int b    = x + ((r & 1) << 3);
  const int qt   = (r >> 1) & 15;
  const int half = (r >> 5) & 1;
  const int q0   = qt * BQ + wave * 64;
  const int kt0  = half * KHALF;

  const float* Qb = Qg + ((size_t)b * SEQ + q0) * DIM;
  float*       Ob = (half ? O1g : O0g) + ((size_t)b * SEQ + q0) * DIM;
  float*       Ls = lsg + (size_t)half * NROWS + b * SEQ + q0;

  // ---- Q fragments (B-operand of S^T = K*Q^T), pre-scaled ----
  half8_t qf[4][2];
  #pragma unroll
  for (int s = 0; s < 4; ++s)
    #pragma unroll
    for (int c = 0; c < 2; ++c) {
      const floatx4 f0 = *(const floatx4*)(Qb + (s * 16 + l16) * DIM + c * 32 + quad * 8);
      const floatx4 f1 = *(const floatx4*)(Qb + (s * 16 + l16) * DIM + c * 32 + quad * 8 + 4);
      half8_t h;
      #pragma unroll
      for (int j = 0; j < 4; ++j) h[j] = (_Float16)(f0[j] * QSCALE);
      #pragma unroll
      for (int j = 0; j < 4; ++j) h[4 + j] = (_Float16)(f1[j] * QSCALE);
      qf[s][c] = h;
    }

  floatx4 oacc2[4][4];   // [dim-tile n][q-slab s]
  float   lsum2[4];
  #pragma unroll
  for (int n = 0; n < 4; ++n)
    #pragma unroll
    for (int s = 0; s < 4; ++s) oacc2[n][s] = (floatx4){0.f, 0.f, 0.f, 0.f};
  #pragma unroll
  for (int s = 0; s < 4; ++s) lsum2[s] = 0.f;

  const _Float16* Kb = Kh + ((size_t)b * NKT + kt0) * TILEH;
  const _Float16* Vb = Vh + ((size_t)b * NKT + kt0) * TILEH;

  // ---------- main loop: no barriers, no LDS; 16 independent 16B loads
  // per tile hoisted by the scheduler, covered by the co-resident wave ----
  #pragma unroll 1
  for (int t = 0; t < KHALF; ++t) {
    const _Float16* KT = Kb + (size_t)t * TILEH;
    const _Float16* VT = Vb + (size_t)t * TILEH;
    #pragma unroll
    for (int h = 0; h < 2; ++h) {
      floatx4 sc2[2][4];
      #pragma unroll
      for (int k2 = 0; k2 < 2; ++k2)
        #pragma unroll
        for (int s = 0; s < 4; ++s) sc2[k2][s] = (floatx4){0.f, 0.f, 0.f, 0.f};
      __builtin_amdgcn_s_setprio(1);
      #pragma unroll
      for (int k2 = 0; k2 < 2; ++k2) {
        const int nk = h * 2 + k2;
        #pragma unroll
        for (int c = 0; c < 2; ++c) {
          const half8_t kf = *(const half8_t*)&KT[(nk * 16 + l16) * 64 +
                                                  ((c * 4 + quad) << 3)];
          #pragma unroll
          for (int s = 0; s < 4; ++s)
            sc2[k2][s] = __builtin_amdgcn_mfma_f32_16x16x32_f16(
                kf, qf[s][c], sc2[k2][s], 0, 0, 0);
        }
      }
      __builtin_amdgcn_s_setprio(0);
      half8_t bfr[4];
      #pragma unroll
      for (int s = 0; s < 4; ++s) {
        half8_t bf;
        #pragma unroll
        for (int j = 0; j < 8; ++j) {
          float p = fast_exp2(sc2[j & 1][s][j >> 1]);
          lsum2[s] += p;
          bf[j] = (_Float16)p;
        }
        bfr[s] = bf;
      }
      __builtin_amdgcn_s_setprio(1);
      #pragma unroll
      for (int n = 0; n < 4; ++n) {
        const half8_t vf = *(const half8_t*)&VT[(n * 16 + l16) * 64 +
                                                ((h * 4 + quad) << 3)];
        #pragma unroll
        for (int s = 0; s < 4; ++s)
          oacc2[n][s] = __builtin_amdgcn_mfma_f32_16x16x32_f16(
              vf, bfr[s], oacc2[n][s], 0, 0, 0);
      }
      __builtin_amdgcn_s_setprio(0);
    }
  }

  // ---------- epilogue: UNNORMALIZED partial O^T + row sums ----------
  #pragma unroll
  for (int s = 0; s < 4; ++s) {
    float v = lsum2[s];
    v += __shfl_xor(v, 16);
    v += __shfl_xor(v, 32);
    if (lane < 16) Ls[s * 16 + l16] = v;
  }
  #pragma unroll
  for (int s = 0; s < 4; ++s)
    #pragma unroll
    for (int n = 0; n < 4; ++n)
      *(floatx4*)&Ob[(s * 16 + l16) * DIM + n * 16 + quad * 4] = oacc2[n][s];
}

// O = (O0 + O1) / (l0 + l1); O0 in d_out (in-place), O1/l0/l1 in ws.
__global__ __launch_bounds__(256)
void attn_combine(float* __restrict__ O, const float* __restrict__ O1,
                  const float* __restrict__ lsg)
{
  const int i = blockIdx.x * 256 + threadIdx.x;   // float4 index
  const int row = i >> 4;
  const float inv = fast_rcp(lsg[row] + lsg[NROWS + row]);
  const float4 a  = ((const float4*)O)[i];
  const float4 bb = ((const float4*)O1)[i];
  float4 r;
  r.x = (a.x + bb.x) * inv;
  r.y = (a.y + bb.y) * inv;
  r.z = (a.z + bb.z) * inv;
  r.w = (a.w + bb.w) * inv;
  ((float4*)O)[i] = r;
}

extern "C" void kernel_launch(void* const* d_in, const int* in_sizes, int n_in,
                              void* d_out, int out_size, void* d_ws, size_t ws_size,
                              hipStream_t stream) {
  const float* Q = (const float*)d_in[0];
  const float* K = (const float*)d_in[1];
  const float* V = (const float*)d_in[2];
  float* O  = (float*)d_out;
  (void)in_sizes; (void)n_in; (void)out_size; (void)ws_size;

  // ws layout (floats): O1 [OELEMS] | Ls [2*NROWS] | Kh,Vh images (f16)
  float*     O1 = (float*)d_ws;
  float*     Ls = O1 + OELEMS;
  _Float16*  Kh = (_Float16*)(Ls + 2 * NROWS);
  _Float16*  Vh = Kh + (size_t)NTILES * TILEH;
  // total: (4.19M + 0.13M)*4B + 2*4.19M*2B = ~34.1 MB (fits: R9 proved >=51 MB)

  prepack_kv<<<dim3(NTILES), dim3(256), 0, stream>>>(K, V, Kh, Vh);
  attn_f16_flash<<<dim3(2 * NBATCH * (SEQ / BQ)), dim3(256), 0, stream>>>(
      Q, Kh, Vh, O, O1, Ls);
  attn_combine<<<dim3(OELEMS / 4 / 256), dim3(256), 0, stream>>>(O, O1, Ls);
}

// Round 4
// 219.866 us; speedup vs baseline: 1.0055x; 1.0055x over previous
//
#include <hip/hip_runtime.h>

// Transposed flash attention, f16 MFMA (16x16x32), no-max softmax, split-K=2.
// R14: R13 (barrier-free, direct-from-L2) proved the traffic model right
// (FETCH 16.4MB -- images fully L2/L3-resident, XCD clustering works) but
// exposed L2 latency: utils fell to ~20%, 141us. Compiler did NOT pipeline
// loads across the tile loop. Fix: explicit software pipeline at h-block
// granularity with named A/B register fragment buffers (static indexing,
// rule #20): while h-block X computes (~300 wave-cyc: 16 QK-MFMA -> softmax
// -> 16 PV-MFMA), the next h-block's 8 fragment loads are in flight.
// Load-to-use distance ~1 h-block > L2 hit latency (~250 cyc).
// Cost: +64 VGPRs buffers -> ~190 peak, safe under launch_bounds(256,2)'s
// 256 cap (R9 disaster was a 128 cap vs 190 live -- NOT this).
// Occupancy falls to ~2 waves/SIMD -- R11/R12 proved occupancy is not the
// lever here; intra-wave ILP is. Floors: MFMA 27.5us, L2 ~31us, VALU ~28us
// -> overlapped target 55-65us (vs 141 R13, 84.5 best-LDS R10).
// Numerics bit-identical to R10/R13.

#define NBATCH 16
#define SEQ    4096
#define DIM    64
#define BQ     256
#define BK     64
#define NKT    (SEQ / BK)      // 64
#define KHALF  (NKT / 2)       // 32 tiles per key-half
#define OELEMS (NBATCH * SEQ * DIM)   // 4194304
#define NROWS  (NBATCH * SEQ)         // 65536
#define NTILES (NBATCH * NKT)         // 1024
#define TILEH  4096                   // halfs per 64x64 tile image (8 KB)

#define QSCALE 0.180336879f   // 0.125 * log2(e)

typedef _Float16 half2_t __attribute__((ext_vector_type(2)));
typedef _Float16 half4_t __attribute__((ext_vector_type(4)));
typedef _Float16 half8_t __attribute__((ext_vector_type(8)));
typedef float    floatx4 __attribute__((ext_vector_type(4)));

__device__ inline float fast_exp2(float x) {
#if __has_builtin(__builtin_amdgcn_exp2f)
  return __builtin_amdgcn_exp2f(x);
#else
  return exp2f(x);
#endif
}
__device__ inline float fast_rcp(float x) {
#if __has_builtin(__builtin_amdgcn_rcpf)
  return __builtin_amdgcn_rcpf(x);
#else
  return 1.0f / x;
#endif
}

// identity layout (linear rows; swizzle was only ever for LDS banks)
__device__ inline int swz(int row, int col) { return row * 64 + col; }

// ---------------- prepack: K,V f32 -> per-tile f16 images ----------------
// One block per (b, kt) tile. K: [key][dim]; V: [dim][slot] (slot-permuted
// PV fragment layout). Staged through LDS for coalesced global dump.
__global__ __launch_bounds__(256, 2)
void prepack_kv(const float* __restrict__ Kg, const float* __restrict__ Vg,
                _Float16* __restrict__ Kh, _Float16* __restrict__ Vh)
{
  __shared__ __align__(16) _Float16 sKi[TILEH];
  __shared__ __align__(16) _Float16 sVi[TILEH];
  const int tid = threadIdx.x;
  const int t16 = tid & 15;
  const int kg  = tid >> 4;
  const int bt  = blockIdx.x;                 // b*64 + kt
  const float* Kt_ = Kg + (size_t)bt * BK * DIM;
  const float* Vt_ = Vg + (size_t)bt * BK * DIM;

  floatx4 kbuf[4], vbuf[4];
  #pragma unroll
  for (int i = 0; i < 4; ++i) {
    const int key = kg + 16 * i;
    kbuf[i] = *(const floatx4*)(Kt_ + key * DIM + t16 * 4);
    vbuf[i] = *(const floatx4*)(Vt_ + key * DIM + t16 * 4);
  }
  #pragma unroll
  for (int i = 0; i < 4; ++i) {               // K: [key][dim]
    const int key = kg + 16 * i;
    half4_t h;
    #pragma unroll
    for (int j = 0; j < 4; ++j) h[j] = (_Float16)kbuf[i][j];
    *(half4_t*)&sKi[swz(key, t16 * 4)] = h;
  }
  {                                           // V: [dim][slot]
    const int vbase = (kg >> 2) * 8 + (kg & 3) * 2;
    #pragma unroll
    for (int e = 0; e < 4; ++e) {
      const int dim = t16 * 4 + e;
      half2_t h0; h0[0] = (_Float16)vbuf[0][e]; h0[1] = (_Float16)vbuf[1][e];
      half2_t h1; h1[0] = (_Float16)vbuf[2][e]; h1[1] = (_Float16)vbuf[3][e];
      *(half2_t*)&sVi[swz(dim, vbase)]      = h0;
      *(half2_t*)&sVi[swz(dim, vbase + 32)] = h1;
    }
  }
  __syncthreads();
  half8_t* Ko = (half8_t*)(Kh + (size_t)bt * TILEH);
  half8_t* Vo = (half8_t*)(Vh + (size_t)bt * TILEH);
  const half8_t* Ks = (const half8_t*)sKi;
  const half8_t* Vs = (const half8_t*)sVi;
  Ko[tid] = Ks[tid]; Ko[tid + 256] = Ks[tid + 256];
  Vo[tid] = Vs[tid]; Vo[tid + 256] = Vs[tid + 256];
}

// ---------------- main kernel: barrier-free, LDS-free, SW-pipelined -------
__global__ __launch_bounds__(256, 2)
void attn_f16_flash(const float* __restrict__ Qg, const _Float16* __restrict__ Kh,
                    const _Float16* __restrict__ Vh, float* __restrict__ O0g,
                    float* __restrict__ O1g, float* __restrict__ lsg)
{
  const int tid  = threadIdx.x;
  const int wave = tid >> 6;
  const int lane = tid & 63;
  const int l16  = lane & 15;
  const int quad = lane >> 4;

  // XCD-clustered decode (bijective over 512 blocks): XCD x = bid&7 gets
  // batches {x, x+8} only -> 2MB K/V image working set per 4MB XCD L2.
  const int bid  = blockIdx.x;
  const int x    = bid & 7;
  const int r    = bid >> 3;                // 0..63
  const int b    = x + ((r & 1) << 3);
  const int qt   = (r >> 1) & 15;
  const int half = (r >> 5) & 1;
  const int q0   = qt * BQ + wave * 64;
  const int kt0  = half * KHALF;

  const float* Qb = Qg + ((size_t)b * SEQ + q0) * DIM;
  float*       Ob = (half ? O1g : O0g) + ((size_t)b * SEQ + q0) * DIM;
  float*       Ls = lsg + (size_t)half * NROWS + b * SEQ + q0;

  // ---- Q fragments (B-operand of S^T = K*Q^T), pre-scaled ----
  half8_t qf[4][2];
  #pragma unroll
  for (int s = 0; s < 4; ++s)
    #pragma unroll
    for (int c = 0; c < 2; ++c) {
      const floatx4 f0 = *(const floatx4*)(Qb + (s * 16 + l16) * DIM + c * 32 + quad * 8);
      const floatx4 f1 = *(const floatx4*)(Qb + (s * 16 + l16) * DIM + c * 32 + quad * 8 + 4);
      half8_t h;
      #pragma unroll
      for (int j = 0; j < 4; ++j) h[j] = (_Float16)(f0[j] * QSCALE);
      #pragma unroll
      for (int j = 0; j < 4; ++j) h[4 + j] = (_Float16)(f1[j] * QSCALE);
      qf[s][c] = h;
    }

  floatx4 oacc2[4][4];   // [dim-tile n][q-slab s]
  float   lsum2[4];
  #pragma unroll
  for (int n = 0; n < 4; ++n)
    #pragma unroll
    for (int s = 0; s < 4; ++s) oacc2[n][s] = (floatx4){0.f, 0.f, 0.f, 0.f};
  #pragma unroll
  for (int s = 0; s < 4; ++s) lsum2[s] = 0.f;

  const _Float16* Kb = Kh + ((size_t)b * NKT + kt0) * TILEH;
  const _Float16* Vb = Vh + ((size_t)b * NKT + kt0) * TILEH;

  // K fragments of h-block H of tile at KT: dst[k2*2+c]
  #define LOADK(dst, KT, H)                                                    \
    do {                                                                       \
      const int nk0 = (H) * 2;                                                 \
      dst[0] = *(const half8_t*)&(KT)[(nk0 * 16 + l16) * 64 + (quad << 3)];    \
      dst[1] = *(const half8_t*)&(KT)[(nk0 * 16 + l16) * 64 + ((4 + quad) << 3)]; \
      dst[2] = *(const half8_t*)&(KT)[((nk0 + 1) * 16 + l16) * 64 + (quad << 3)]; \
      dst[3] = *(const half8_t*)&(KT)[((nk0 + 1) * 16 + l16) * 64 + ((4 + quad) << 3)]; \
    } while (0)

  // V fragments of h-block H of tile at VT: dst[n]
  #define LOADV(dst, VT, H)                                                    \
    do {                                                                       \
      _Pragma("unroll")                                                        \
      for (int n = 0; n < 4; ++n)                                              \
        dst[n] = *(const half8_t*)&(VT)[(n * 16 + l16) * 64 +                  \
                                        (((H) * 4 + quad) << 3)];              \
    } while (0)

  // compute one h-block from register fragments kfX[4], vfX[4]
  #define HBLOCK(kfX, vfX)                                                     \
    do {                                                                       \
      floatx4 sc2[2][4];                                                       \
      _Pragma("unroll")                                                        \
      for (int k2 = 0; k2 < 2; ++k2)                                           \
        _Pragma("unroll")                                                      \
        for (int s = 0; s < 4; ++s) sc2[k2][s] = (floatx4){0.f, 0.f, 0.f, 0.f};\
      __builtin_amdgcn_s_setprio(1);                                           \
      _Pragma("unroll")                                                        \
      for (int k2 = 0; k2 < 2; ++k2)                                           \
        _Pragma("unroll")                                                      \
        for (int c = 0; c < 2; ++c)                                            \
          _Pragma("unroll")                                                    \
          for (int s = 0; s < 4; ++s)                                          \
            sc2[k2][s] = __builtin_amdgcn_mfma_f32_16x16x32_f16(               \
                kfX[k2 * 2 + c], qf[s][c], sc2[k2][s], 0, 0, 0);               \
      __builtin_amdgcn_s_setprio(0);                                           \
      half8_t bfr[4];                                                          \
      _Pragma("unroll")                                                        \
      for (int s = 0; s < 4; ++s) {                                            \
        half8_t bf;                                                            \
        _Pragma("unroll")                                                      \
        for (int j = 0; j < 8; ++j) {                                          \
          float p = fast_exp2(sc2[j & 1][s][j >> 1]);                          \
          lsum2[s] += p;                                                       \
          bf[j] = (_Float16)p;                                                 \
        }                                                                      \
        bfr[s] = bf;                                                           \
      }                                                                        \
      __builtin_amdgcn_s_setprio(1);                                           \
      _Pragma("unroll")                                                        \
      for (int n = 0; n < 4; ++n)                                              \
        _Pragma("unroll")                                                      \
        for (int s = 0; s < 4; ++s)                                            \
          oacc2[n][s] = __builtin_amdgcn_mfma_f32_16x16x32_f16(                \
              vfX[n], bfr[s], oacc2[n][s], 0, 0, 0);                           \
      __builtin_amdgcn_s_setprio(0);                                           \
    } while (0)

  // ---------- software-pipelined main loop ----------
  // Named A/B buffers (static indices). While h-block A computes, B's loads
  // are in flight (and vice versa). Load-to-use distance ~1 h-block.
  half8_t kfA[4], vfA[4], kfB[4], vfB[4];
  const _Float16* KT = Kb;
  const _Float16* VT = Vb;

  LOADK(kfA, KT, 0);
  LOADV(vfA, VT, 0);

  #pragma unroll 1
  for (int t = 0; t < KHALF - 1; ++t) {
    LOADK(kfB, KT, 1);            // prefetch h=1 of tile t
    LOADV(vfB, VT, 1);
    HBLOCK(kfA, vfA);             // compute h=0 of tile t
    LOADK(kfA, KT + TILEH, 0);    // prefetch h=0 of tile t+1
    LOADV(vfA, VT + TILEH, 0);
    HBLOCK(kfB, vfB);             // compute h=1 of tile t
    KT += TILEH;
    VT += TILEH;
  }
  LOADK(kfB, KT, 1);              // last tile, h=1
  LOADV(vfB, VT, 1);
  HBLOCK(kfA, vfA);
  HBLOCK(kfB, vfB);

  // ---------- epilogue: UNNORMALIZED partial O^T + row sums ----------
  #pragma unroll
  for (int s = 0; s < 4; ++s) {
    float v = lsum2[s];
    v += __shfl_xor(v, 16);
    v += __shfl_xor(v, 32);
    if (lane < 16) Ls[s * 16 + l16] = v;
  }
  #pragma unroll
  for (int s = 0; s < 4; ++s)
    #pragma unroll
    for (int n = 0; n < 4; ++n)
      *(floatx4*)&Ob[(s * 16 + l16) * DIM + n * 16 + quad * 4] = oacc2[n][s];

  #undef LOADK
  #undef LOADV
  #undef HBLOCK
}

// O = (O0 + O1) / (l0 + l1); O0 in d_out (in-place), O1/l0/l1 in ws.
__global__ __launch_bounds__(256)
void attn_combine(float* __restrict__ O, const float* __restrict__ O1,
                  const float* __restrict__ lsg)
{
  const int i = blockIdx.x * 256 + threadIdx.x;   // float4 index
  const int row = i >> 4;
  const float inv = fast_rcp(lsg[row] + lsg[NROWS + row]);
  const float4 a  = ((const float4*)O)[i];
  const float4 bb = ((const float4*)O1)[i];
  float4 r;
  r.x = (a.x + bb.x) * inv;
  r.y = (a.y + bb.y) * inv;
  r.z = (a.z + bb.z) * inv;
  r.w = (a.w + bb.w) * inv;
  ((float4*)O)[i] = r;
}

extern "C" void kernel_launch(void* const* d_in, const int* in_sizes, int n_in,
                              void* d_out, int out_size, void* d_ws, size_t ws_size,
                              hipStream_t stream) {
  const float* Q = (const float*)d_in[0];
  const float* K = (const float*)d_in[1];
  const float* V = (const float*)d_in[2];
  float* O  = (float*)d_out;
  (void)in_sizes; (void)n_in; (void)out_size; (void)ws_size;

  // ws layout (floats): O1 [OELEMS] | Ls [2*NROWS] | Kh,Vh images (f16)
  float*     O1 = (float*)d_ws;
  float*     Ls = O1 + OELEMS;
  _Float16*  Kh = (_Float16*)(Ls + 2 * NROWS);
  _Float16*  Vh = Kh + (size_t)NTILES * TILEH;
  // total: (4.19M + 0.13M)*4B + 2*4.19M*2B = ~34.1 MB (fits: R9 proved >=51 MB)

  prepack_kv<<<dim3(NTILES), dim3(256), 0, stream>>>(K, V, Kh, Vh);
  attn_f16_flash<<<dim3(2 * NBATCH * (SEQ / BQ)), dim3(256), 0, stream>>>(
      Q, Kh, Vh, O, O1, Ls);
  attn_combine<<<dim3(OELEMS / 4 / 256), dim3(256), 0, stream>>>(O, O1, Ls);
}

// Round 5
// 163.615 us; speedup vs baseline: 1.3512x; 1.3438x over previous
//
#include <hip/hip_runtime.h>

// Transposed flash attention, f16 MFMA (16x16x32), no-max softmax, split-K=2.
// R15: R13/R14 proved direct-from-L2 streaming is latency-bound under
// contention (141us, utils 20%, FETCH 16MB) -- LDS staging (R10, 84.5us) was
// right; its residual stall is the __syncthreads() vmcnt(0) full drain of
// the gload_lds prefetch at EVERY barrier (guide m131-m141's ~20% structural
// stall). Fix = T4 counted vmcnt across RAW barriers: 4-buffer LDS ring
// (64KB, still 2 blocks/CU), prefetch distance 2 tiles; per tile:
//   s_waitcnt vmcnt(4); s_barrier; ASYNC(t+2); COMPUTE(t)
// Per-wave FIFO guarantee (own loads older than newest 4 done) + barrier =
// collective guarantee; tile t+1's 4 loads stay in flight across the
// barrier (cp.async.wait_group analog). WAR safe: buf (t+2)&3 last read at
// phase t-2, sealed by two barriers. sched_barrier(0) after each wait pair
// (rule #18); setprio(1) around MFMA (T5, m191 +4-7% attn). XCD-clustered
// decode kept from R13 (FETCH 49->16MB, verified). Numerics bit-identical
// to R10. launch_bounds(256,2) -- NEVER promise more (R9: 7x spill).
// Failure read: flat ~85us -> drain wasn't the stall -> split COMPUTE into
// interleaved sub-phases next.

#define NBATCH 16
#define SEQ    4096
#define DIM    64
#define BQ     256
#define BK     64
#define NKT    (SEQ / BK)      // 64
#define KHALF  (NKT / 2)       // 32 tiles per key-half
#define OELEMS (NBATCH * SEQ * DIM)   // 4194304
#define NROWS  (NBATCH * SEQ)         // 65536
#define NTILES (NBATCH * NKT)         // 1024
#define TILEH  4096                   // halfs per 64x64 tile image (8 KB)

#define QSCALE 0.180336879f   // 0.125 * log2(e)

typedef _Float16 half2_t __attribute__((ext_vector_type(2)));
typedef _Float16 half4_t __attribute__((ext_vector_type(4)));
typedef _Float16 half8_t __attribute__((ext_vector_type(8)));
typedef float    floatx4 __attribute__((ext_vector_type(4)));

__device__ inline float fast_exp2(float x) {
#if __has_builtin(__builtin_amdgcn_exp2f)
  return __builtin_amdgcn_exp2f(x);
#else
  return exp2f(x);
#endif
}
__device__ inline float fast_rcp(float x) {
#if __has_builtin(__builtin_amdgcn_rcpf)
  return __builtin_amdgcn_rcpf(x);
#else
  return 1.0f / x;
#endif
}

// swizzled offset in halfs for element (row, col) of a 64x64 half tile
__device__ inline int swz(int row, int col) {
  return row * 64 + ((((col >> 3) ^ ((row >> 1) & 7)) << 3) | (col & 7));
}

// async 16B global->LDS copy: lds dest is wave-uniform; HW adds lane*16
__device__ inline void async16(const void* g, void* l) {
  __builtin_amdgcn_global_load_lds(
      (const __attribute__((address_space(1))) void*)g,
      (__attribute__((address_space(3))) void*)l, 16, 0, 0);
}

// ---------------- prepack: K,V f32 -> per-tile f16 LDS images ----------------
// One block per (b, kt) tile. R8's verified staging/swizzle logic, then
// dumps the LDS image flat to global. (Swizzled layout restored: the main
// kernel stages through LDS again, banks matter.)
__global__ __launch_bounds__(256, 2)
void prepack_kv(const float* __restrict__ Kg, const float* __restrict__ Vg,
                _Float16* __restrict__ Kh, _Float16* __restrict__ Vh)
{
  __shared__ __align__(16) _Float16 sKi[TILEH];
  __shared__ __align__(16) _Float16 sVi[TILEH];
  const int tid = threadIdx.x;
  const int t16 = tid & 15;
  const int kg  = tid >> 4;
  const int bt  = blockIdx.x;                 // b*64 + kt
  const float* Kt_ = Kg + (size_t)bt * BK * DIM;
  const float* Vt_ = Vg + (size_t)bt * BK * DIM;

  floatx4 kbuf[4], vbuf[4];
  #pragma unroll
  for (int i = 0; i < 4; ++i) {
    const int key = kg + 16 * i;
    kbuf[i] = *(const floatx4*)(Kt_ + key * DIM + t16 * 4);
    vbuf[i] = *(const floatx4*)(Vt_ + key * DIM + t16 * 4);
  }
  #pragma unroll
  for (int i = 0; i < 4; ++i) {               // K: [key][dim] swizzled
    const int key = kg + 16 * i;
    half4_t h;
    #pragma unroll
    for (int j = 0; j < 4; ++j) h[j] = (_Float16)kbuf[i][j];
    *(half4_t*)&sKi[swz(key, t16 * 4)] = h;
  }
  {                                           // V: [dim][slot] swizzled
    const int vbase = (kg >> 2) * 8 + (kg & 3) * 2;
    #pragma unroll
    for (int e = 0; e < 4; ++e) {
      const int dim = t16 * 4 + e;
      half2_t h0; h0[0] = (_Float16)vbuf[0][e]; h0[1] = (_Float16)vbuf[1][e];
      half2_t h1; h1[0] = (_Float16)vbuf[2][e]; h1[1] = (_Float16)vbuf[3][e];
      *(half2_t*)&sVi[swz(dim, vbase)]      = h0;
      *(half2_t*)&sVi[swz(dim, vbase + 32)] = h1;
    }
  }
  __syncthreads();
  half8_t* Ko = (half8_t*)(Kh + (size_t)bt * TILEH);
  half8_t* Vo = (half8_t*)(Vh + (size_t)bt * TILEH);
  const half8_t* Ks = (const half8_t*)sKi;
  const half8_t* Vs = (const half8_t*)sVi;
  Ko[tid] = Ks[tid]; Ko[tid + 256] = Ks[tid + 256];
  Vo[tid] = Vs[tid]; Vo[tid + 256] = Vs[tid + 256];
}

// ---------------- main kernel ----------------
__global__ __launch_bounds__(256, 2)
void attn_f16_flash(const float* __restrict__ Qg, const _Float16* __restrict__ Kh,
                    const _Float16* __restrict__ Vh, float* __restrict__ O0g,
                    float* __restrict__ O1g, float* __restrict__ lsg)
{
  __shared__ __align__(16) _Float16 sT[4][2 * TILEH];  // ring: [buf][ K | V ]

  const int tid  = threadIdx.x;
  const int wave = tid >> 6;
  const int lane = tid & 63;
  const int l16  = lane & 15;
  const int quad = lane >> 4;
  const int hK   = (l16 >> 1) & 7;

  // XCD-clustered decode (bijective over 512 blocks): XCD x = bid&7 gets
  // batches {x, x+8} only -> 2MB K/V image working set per 4MB XCD L2.
  const int bid  = blockIdx.x;
  const int x    = bid & 7;
  const int r    = bid >> 3;                // 0..63
  const int b    = x + ((r & 1) << 3);
  const int qt   = (r >> 1) & 15;
  const int half = (r >> 5) & 1;
  const int q0   = qt * BQ + wave * 64;
  const int kt0  = half * KHALF;

  const float* Qb = Qg + ((size_t)b * SEQ + q0) * DIM;
  float*       Ob = (half ? O1g : O0g) + ((size_t)b * SEQ + q0) * DIM;
  float*       Ls = lsg + (size_t)half * NROWS + b * SEQ + q0;

  // ---- Q fragments (B-operand of S^T = K*Q^T), pre-scaled ----
  half8_t qf[4][2];
  #pragma unroll
  for (int s = 0; s < 4; ++s)
    #pragma unroll
    for (int c = 0; c < 2; ++c) {
      const floatx4 f0 = *(const floatx4*)(Qb + (s * 16 + l16) * DIM + c * 32 + quad * 8);
      const floatx4 f1 = *(const floatx4*)(Qb + (s * 16 + l16) * DIM + c * 32 + quad * 8 + 4);
      half8_t h;
      #pragma unroll
      for (int j = 0; j < 4; ++j) h[j] = (_Float16)(f0[j] * QSCALE);
      #pragma unroll
      for (int j = 0; j < 4; ++j) h[4 + j] = (_Float16)(f1[j] * QSCALE);
      qf[s][c] = h;
    }

  floatx4 oacc2[4][4];   // [dim-tile n][q-slab s]
  float   lsum2[4];
  #pragma unroll
  for (int n = 0; n < 4; ++n)
    #pragma unroll
    for (int s = 0; s < 4; ++s) oacc2[n][s] = (floatx4){0.f, 0.f, 0.f, 0.f};
  #pragma unroll
  for (int s = 0; s < 4; ++s) lsum2[s] = 0.f;

  // ---- async staging: 4 x 16B-per-lane copies per wave per tile ----
  #define ASYNC(KT, BUF)                                                       \
    do {                                                                       \
      const char* gk = (const char*)(Kh + ((size_t)b * NKT + (KT)) * TILEH)    \
                       + wave * 2048;                                          \
      const char* gv = (const char*)(Vh + ((size_t)b * NKT + (KT)) * TILEH)    \
                       + wave * 2048;                                          \
      char* lk = (char*)(&sT[BUF][0])     + wave * 2048;                       \
      char* lv = (char*)(&sT[BUF][TILEH]) + wave * 2048;                       \
      async16(gk + lane * 16,        lk);                                      \
      async16(gk + 1024 + lane * 16, lk + 1024);                               \
      async16(gv + lane * 16,        lv);                                      \
      async16(gv + 1024 + lane * 16, lv + 1024);                               \
    } while (0)

  // ---- compute one 64-key tile from ring buffer BUF ----
  #define COMPUTE(BUF)                                                         \
    do {                                                                       \
      const _Float16* SKB = &sT[BUF][0];                                       \
      const _Float16* SVB = &sT[BUF][TILEH];                                   \
      _Pragma("unroll")                                                        \
      for (int h = 0; h < 2; ++h) {                                            \
        floatx4 sc2[2][4];                                                     \
        _Pragma("unroll")                                                      \
        for (int k2 = 0; k2 < 2; ++k2)                                         \
          _Pragma("unroll")                                                    \
          for (int s = 0; s < 4; ++s) sc2[k2][s] = (floatx4){0.f, 0.f, 0.f, 0.f};\
        __builtin_amdgcn_s_setprio(1);                                         \
        _Pragma("unroll")                                                      \
        for (int k2 = 0; k2 < 2; ++k2) {                                       \
          const int nk = h * 2 + k2;                                           \
          _Pragma("unroll")                                                    \
          for (int c = 0; c < 2; ++c) {                                        \
            half8_t kf = *(const half8_t*)&SKB[(nk * 16 + l16) * 64 +          \
                                               (((c * 4 + quad) ^ hK) << 3)];  \
            _Pragma("unroll")                                                  \
            for (int s = 0; s < 4; ++s)                                        \
              sc2[k2][s] = __builtin_amdgcn_mfma_f32_16x16x32_f16(             \
                  kf, qf[s][c], sc2[k2][s], 0, 0, 0);                          \
          }                                                                    \
        }                                                                      \
        __builtin_amdgcn_s_setprio(0);                                         \
        half8_t bfr[4];                                                        \
        _Pragma("unroll")                                                      \
        for (int s = 0; s < 4; ++s) {                                          \
          half8_t bf;                                                          \
          _Pragma("unroll")                                                    \
          for (int j = 0; j < 8; ++j) {                                        \
            float p = fast_exp2(sc2[j & 1][s][j >> 1]);                        \
            lsum2[s] += p;                                                     \
            bf[j] = (_Float16)p;                                               \
          }                                                                    \
          bfr[s] = bf;                                                         \
        }                                                                      \
        __builtin_amdgcn_s_setprio(1);                                         \
        _Pragma("unroll")                                                      \
        for (int n = 0; n < 4; ++n) {                                          \
          half8_t vf = *(const half8_t*)&SVB[(n * 16 + l16) * 64 +             \
                                             (((h * 4 + quad) ^ hK) << 3)];    \
          _Pragma("unroll")                                                    \
          for (int s = 0; s < 4; ++s)                                          \
            oacc2[n][s] = __builtin_amdgcn_mfma_f32_16x16x32_f16(              \
                vf, bfr[s], oacc2[n][s], 0, 0, 0);                             \
        }                                                                      \
        __builtin_amdgcn_s_setprio(0);                                         \
      }                                                                        \
    } while (0)

  // counted-vmcnt phase gate: my loads older than newest N done + barrier
  // => all waves' data for the gated tile landed. Loads stay in flight.
  #define GATE(N)                                                              \
    do {                                                                       \
      asm volatile("s_waitcnt vmcnt(" #N ")" ::: "memory");                    \
      __builtin_amdgcn_s_barrier();                                            \
      __builtin_amdgcn_sched_barrier(0);                                       \
    } while (0)

  // ---------- main loop: 1 raw barrier/tile, prefetch distance 2 ----------
  ASYNC(kt0 + 0, 0);
  ASYNC(kt0 + 1, 1);

  #pragma unroll 1
  for (int t = 0; t < KHALF - 2; ++t) {
    GATE(4);                       // tile t's loads done; t+1's in flight
    ASYNC(kt0 + t + 2, (t + 2) & 3);
    COMPUTE(t & 3);
  }
  GATE(4);                         // tile KHALF-2 ready; KHALF-1 in flight
  COMPUTE((KHALF - 2) & 3);
  GATE(0);                         // drain last tile
  COMPUTE((KHALF - 1) & 3);

  // ---------- epilogue: UNNORMALIZED partial O^T + row sums ----------
  #pragma unroll
  for (int s = 0; s < 4; ++s) {
    float v = lsum2[s];
    v += __shfl_xor(v, 16);
    v += __shfl_xor(v, 32);
    if (lane < 16) Ls[s * 16 + l16] = v;
  }
  #pragma unroll
  for (int s = 0; s < 4; ++s)
    #pragma unroll
    for (int n = 0; n < 4; ++n)
      *(floatx4*)&Ob[(s * 16 + l16) * DIM + n * 16 + quad * 4] = oacc2[n][s];

  #undef ASYNC
  #undef COMPUTE
  #undef GATE
}

// O = (O0 + O1) / (l0 + l1); O0 in d_out (in-place), O1/l0/l1 in ws.
__global__ __launch_bounds__(256)
void attn_combine(float* __restrict__ O, const float* __restrict__ O1,
                  const float* __restrict__ lsg)
{
  const int i = blockIdx.x * 256 + threadIdx.x;   // float4 index
  const int row = i >> 4;
  const float inv = fast_rcp(lsg[row] + lsg[NROWS + row]);
  const float4 a  = ((const float4*)O)[i];
  const float4 bb = ((const float4*)O1)[i];
  float4 r;
  r.x = (a.x + bb.x) * inv;
  r.y = (a.y + bb.y) * inv;
  r.z = (a.z + bb.z) * inv;
  r.w = (a.w + bb.w) * inv;
  ((float4*)O)[i] = r;
}

extern "C" void kernel_launch(void* const* d_in, const int* in_sizes, int n_in,
                              void* d_out, int out_size, void* d_ws, size_t ws_size,
                              hipStream_t stream) {
  const float* Q = (const float*)d_in[0];
  const float* K = (const float*)d_in[1];
  const float* V = (const float*)d_in[2];
  float* O  = (float*)d_out;
  (void)in_sizes; (void)n_in; (void)out_size; (void)ws_size;

  // ws layout (floats): O1 [OELEMS] | Ls [2*NROWS] | Kh,Vh images (f16)
  float*     O1 = (float*)d_ws;
  float*     Ls = O1 + OELEMS;
  _Float16*  Kh = (_Float16*)(Ls + 2 * NROWS);
  _Float16*  Vh = Kh + (size_t)NTILES * TILEH;
  // total: (4.19M + 0.13M)*4B + 2*4.19M*2B = ~34.1 MB (fits: R9 proved >=51 MB)

  prepack_kv<<<dim3(NTILES), dim3(256), 0, stream>>>(K, V, Kh, Vh);
  attn_f16_flash<<<dim3(2 * NBATCH * (SEQ / BQ)), dim3(256), 0, stream>>>(
      Q, Kh, Vh, O, O1, Ls);
  attn_combine<<<dim3(OELEMS / 4 / 256), dim3(256), 0, stream>>>(O, O1, Ls);
}